// Round 11
// baseline (177.495 us; speedup 1.0000x reference)
//
#include <hip/hip_runtime.h>

#define VOCAB 1024
#define HIDDEN 64
#define N_POS 131072            // 32*64*64 positions
#define Q_ELEMS 8388608
#define BPOS 512                // positions per block
#define NBLK 256                // 1 block per CU

// d_out layout (floats): [0]=loss, [1..8388608]=quantized_st (NCHW),
// [8388609]=perplexity, [8388610..]=one_hot [131072,1024]
#define OUT_Q_OFF 1
#define OUT_PPL_OFF 8388609
#define OUT_OH_OFF 8388610ULL
#define OH_SLOTS 33554431      // float4 slots between the head/tail float2s

typedef __attribute__((ext_vector_type(8))) short short8v;  // bf16x8 MFMA frag
typedef __attribute__((ext_vector_type(4))) float f32x4;

__device__ __forceinline__ short bf16r(float f) {
    union { float f; unsigned u; } v; v.f = f;
    unsigned r = v.u + 0x7FFFu + ((v.u >> 16) & 1u);   // RNE
    return (short)(r >> 16);
}

// 512 threads, 1 block/CU. Waves 0-3: compute (512 positions). Waves 4-7:
// PURE zero-fill of the block's 2 MB one_hot slice -- no barriers, no LDS
// after the single staging barrier, exactly the fillBuffer condition that
// sustains 6.6 TB/s at ~4 waves/CU. The data-dependent 1.0 is scattered by
// a separate stream-ordered kernel, so fill and compute never interact.
__global__ __launch_bounds__(512, 1) void vq_fused(
    const float* __restrict__ in, const float* __restrict__ cb,
    float* __restrict__ out, float* __restrict__ ws_loss,
    unsigned* __restrict__ counts, unsigned short* __restrict__ ws_idx)
{
    __shared__ short cbs[VOCAB * HIDDEN];     // 128 KB, XOR-swizzled bf16
    __shared__ float bsqs[VOCAB];             // 4 KB, -0.5*|c|^2
    __shared__ unsigned whist[4][VOCAB];      // 16 KB, per-compute-wave hist

    const int tid  = threadIdx.x;
    const int wid  = tid >> 6;
    const int lane = tid & 63;
    const int bid  = blockIdx.x;
    const int base = bid * BPOS;
    const int b    = base >> 12;       // NCHW batch index, uniform per block
    const int hw0  = base & 4095;

    for (int k = tid; k < 4 * VOCAB; k += 512) ((unsigned*)whist)[k] = 0u;

    // ---- stage the whole codebook as swizzled bf16 (all 8 waves) ----
    {
        const float4* src = (const float4*)cb;
#pragma unroll 4
        for (int it = 0; it < 32; ++it) {
            int i = tid + it * 512;
            int row = i >> 4, c4 = i & 15;
            float4 v = src[i];
            float ss = v.x * v.x + v.y * v.y + v.z * v.z + v.w * v.w;
            ss += __shfl_xor(ss, 1);
            ss += __shfl_xor(ss, 2);
            ss += __shfl_xor(ss, 4);
            ss += __shfl_xor(ss, 8);
            unsigned lo = ((unsigned)(unsigned short)bf16r(v.x))
                        | ((unsigned)(unsigned short)bf16r(v.y) << 16);
            unsigned hi = ((unsigned)(unsigned short)bf16r(v.z))
                        | ((unsigned)(unsigned short)bf16r(v.w) << 16);
            int boff = row * 128 + ((c4 * 8) ^ ((row & 7) << 4));
            *(uint2*)((char*)cbs + boff) = make_uint2(lo, hi);
            if (c4 == 0) bsqs[row] = -0.5f * ss;
        }
    }

    // ---- compute waves also pre-load their x fragments (overlaps staging) ----
    const int l15 = lane & 15, kg = lane >> 4;
    const int kg4 = kg << 2, kgb = kg << 4;
    short8v xf[2][4][2];
    float xsq[2][4];
    if (wid < 4) {
#pragma unroll
        for (int t = 0; t < 2; ++t)
#pragma unroll
        for (int bt = 0; bt < 4; ++bt) {
            xsq[t][bt] = 0.f;
#pragma unroll
            for (int kh = 0; kh < 2; ++kh) {
                const float* xp = in + (size_t)b * 262144
                                + (size_t)(kh * 32 + kg * 8) * 4096
                                + hw0 + t * 256 + wid * 64 + bt * 16 + l15;
                short8v v;
#pragma unroll
                for (int e = 0; e < 8; ++e) {
                    float x = xp[(size_t)e * 4096];
                    xsq[t][bt] = fmaf(x, x, xsq[t][bt]);
                    v[e] = bf16r(x);
                }
                xf[t][bt][kh] = v;
            }
        }
    }

    __syncthreads();     // the ONLY block barrier: staging complete

    if (wid < 4) {
        // ======================= compute waves (no more barriers) =======
        float lsum = 0.f;
#pragma unroll
        for (int t = 0; t < 2; ++t) {
            float rm[4];
#pragma unroll
            for (int bt = 0; bt < 4; ++bt) rm[bt] = -3.4e38f;

            for (int ct = 0; ct < 64; ++ct) {
                const int rbase = ct * 16 + l15;           // A-frag row = code
                const char* arow = (const char*)cbs + rbase * 128;
                const int sw = (rbase & 7) << 4;
                short8v a0 = *(const short8v*)(arow + (kgb ^ sw));          // k 0..31
                short8v a1 = *(const short8v*)(arow + ((64 + kgb) ^ sw));   // k 32..63
                f32x4 bsq4 = *(const f32x4*)&bsqs[ct * 16 + kg4];
                const unsigned jb = (unsigned)(ct * 16 + kg4);
#pragma unroll
                for (int bt = 0; bt < 4; ++bt) {
                    f32x4 acc = bsq4;
                    acc = __builtin_amdgcn_mfma_f32_16x16x32_bf16(a0, xf[t][bt][0], acc, 0, 0, 0);
                    acc = __builtin_amdgcn_mfma_f32_16x16x32_bf16(a1, xf[t][bt][1], acc, 0, 0, 0);
#pragma unroll
                    for (int r = 0; r < 4; ++r) {
                        unsigned pj = (__float_as_uint(acc[r]) & 0xFFFFFC00u) | (jb + r);
                        rm[bt] = fmaxf(rm[bt], __uint_as_float(pj));
                    }
                }
            }

            // full butterfly over kg: every lane gets max+|x|^2 for its column
            float mred[4], xred[4];
#pragma unroll
            for (int bt = 0; bt < 4; ++bt) {
                float m = rm[bt], xs = xsq[t][bt];
                m  = fmaxf(m, __shfl_xor(m, 16));
                xs += __shfl_xor(xs, 16);
                m  = fmaxf(m, __shfl_xor(m, 32));
                xs += __shfl_xor(xs, 32);
                mred[bt] = m; xred[bt] = xs;
            }
            const int sel = kg;    // lane L owns col L: bt == kg
            const float m  = sel == 0 ? mred[0] : sel == 1 ? mred[1]
                           : sel == 2 ? mred[2] : mred[3];
            const float xs = sel == 0 ? xred[0] : sel == 1 ? xred[1]
                           : sel == 2 ? xred[2] : xred[3];
            const unsigned mu = __float_as_uint(m);
            const int   jf   = (int)(mu & 1023u);
            const float mval = __uint_as_float(mu & 0xFFFFFC00u);
            lsum += xs - 2.f * mval;   // |x-c|^2 = |x|^2 - 2(x.c - 0.5|c|^2)

            const int p = t * 256 + wid * 64 + lane;       // block-rel position
            ws_idx[base + p] = (unsigned short)jf;
            atomicAdd(&whist[wid][jf], 1u);

            // q write: gather fp32 code row, store NCHW (quantized_st == q)
            const float4* cr4 = (const float4*)(cb + (size_t)jf * HIDDEN);
            float* qp = out + OUT_Q_OFF + (size_t)b * 262144 + hw0 + p;
#pragma unroll
            for (int c4 = 0; c4 < 16; ++c4) {
                float4 v = cr4[c4];
                __builtin_nontemporal_store(v.x, &qp[(size_t)(4 * c4 + 0) * 4096]);
                __builtin_nontemporal_store(v.y, &qp[(size_t)(4 * c4 + 1) * 4096]);
                __builtin_nontemporal_store(v.z, &qp[(size_t)(4 * c4 + 2) * 4096]);
                __builtin_nontemporal_store(v.w, &qp[(size_t)(4 * c4 + 3) * 4096]);
            }
        }

        // flush this wave's private histogram (its own ds-atomics only)
        for (int k = lane; k < VOCAB; k += 64) {
            unsigned h = whist[wid][k];
            if (h) atomicAdd(&counts[k], h);
        }
#pragma unroll
        for (int off = 32; off; off >>= 1) lsum += __shfl_down(lsum, off);
        if (lane == 0) atomicAdd(&ws_loss[bid & 63], lsum);
    } else {
        // ======================= pure fill waves =========================
        const int fw = wid - 4;                  // 0..3
        float* ohbase = out + OUT_OH_OFF;
        f32x4* oh4 = (f32x4*)(ohbase + 2);       // 16B aligned
        const f32x4 z = {0.f, 0.f, 0.f, 0.f};
        if (bid == 0 && fw == 0 && lane == 0) {          // head floats 0..1
            ohbase[0] = 0.f; ohbase[1] = 0.f;
        }
        if (bid == NBLK - 1 && fw == 3 && lane == 63) {  // tail floats
            ohbase[(size_t)N_POS * VOCAB - 2] = 0.f;
            ohbase[(size_t)N_POS * VOCAB - 1] = 0.f;
        }
        size_t s = (size_t)bid * 131072 + (size_t)fw * 32768 + lane;
#pragma unroll 4
        for (int k = 0; k < 512; ++k, s += 64)
            if (s < OH_SLOTS) __builtin_nontemporal_store(z, &oh4[s]);
    }
}

// stream-ordered after vq_fused: all zeros are committed; drop in the 1.0s
__global__ void vq_scatter(const unsigned short* __restrict__ ws_idx,
                           float* __restrict__ out)
{
    const int n = blockIdx.x * 256 + threadIdx.x;
    out[OUT_OH_OFF + (size_t)n * VOCAB + ws_idx[n]] = 1.0f;
}

__global__ void vq_finalize(const unsigned* __restrict__ counts,
                            const float* __restrict__ ws_loss,
                            float* __restrict__ out)
{
    __shared__ double red[4];
    const int tid = threadIdx.x;
    double s = 0.0;
    for (int k = tid; k < VOCAB; k += 256) {
        double p = (double)counts[k] / (double)N_POS;
        s += -p * log(p + 1e-10);
    }
#pragma unroll
    for (int off = 32; off; off >>= 1) s += __shfl_down(s, off);
    if ((tid & 63) == 0) red[tid >> 6] = s;
    __syncthreads();
    if (tid == 0) {
        double e = red[0] + red[1] + red[2] + red[3];
        out[OUT_PPL_OFF] = (float)exp(e);
        float l = 0.f;
#pragma unroll
        for (int k = 0; k < 64; ++k) l += ws_loss[k];
        out[0] = l * 1.25f / (float)Q_ELEMS;
    }
}

extern "C" void kernel_launch(void* const* d_in, const int* in_sizes, int n_in,
                              void* d_out, int out_size, void* d_ws, size_t ws_size,
                              hipStream_t stream) {
    const float* in = (const float*)d_in[0];
    const float* cb = (const float*)d_in[1];
    float* out = (float*)d_out;

    // ws: [0,256)B loss slots | [256,4352)B counts | [8192,270336)B idx u16
    float*          ws_loss = (float*)d_ws;
    unsigned*       counts  = (unsigned*)d_ws + 64;
    unsigned short* ws_idx  = (unsigned short*)((char*)d_ws + 8192);

    (void)hipMemsetAsync(d_ws, 0, 4352, stream);      // zero loss slots + counts
    vq_fused<<<NBLK, 512, 0, stream>>>(in, cb, out, ws_loss, counts, ws_idx);
    vq_scatter<<<N_POS / 256, 256, 0, stream>>>(ws_idx, out);
    vq_finalize<<<1, 256, 0, stream>>>(counts, ws_loss, out);
}